// Round 7
// baseline (156.805 us; speedup 1.0000x reference)
//
#include <hip/hip_runtime.h>
#include <stdint.h>

#define IMG 224
#define OUT_DIM 112
#define NCH 16
#define TILE_Y 32          // conv rows per block (full 224-wide strip)
#define R_ROWS 36          // TILE_Y + 4 halo rows
#define A_ROWS 20          // rows staged before first barrier (covers conv rows 0..15)
#define HJ 116             // dwords per plane row: 2 front pad + 112 pairs + 2 tail pad
#define HSZ (R_ROWS * HJ)  // dwords per parity plane
#define QW 56              // float4 quads per image row
#define A_ITEMS (A_ROWS * QW)   // 1120
#define T_ITEMS (R_ROWS * QW)   // 2016

typedef _Float16 h8t  __attribute__((ext_vector_type(8)));
typedef float    f32x4 __attribute__((ext_vector_type(4)));
typedef uint32_t u32x4 __attribute__((ext_vector_type(4)));

// Implicit-GEMM conv (M=16 pixels, N=16 ch, K=32 = 25 taps + zero pad), one
// mfma_f32_16x16x32_f16 per conv row per 16-pixel subtile. Verified mapping:
//   B lane (ch=l&15, g=l>>4): k=8g+j -> (dy=g, dx=j) j<5; j=6,7 -> (dy=4, dx=2g,2g+1)
//   A lane (pp=l&15, g=l>>4): pairs (dx0,1)(dx2,3)(dx4,junk*0) of row y+g
//                             + pair (dx 2g,2g+1) of row y+4
//   D lane (pp,g) reg r: pixel 4g+r, channel pp -> 2x2 pool in-lane + across rows.
// LDS: parity-split pair planes, pair C = (in[C], in[C+1]) at plane[C&1],
//   row dword 2 + floor(C/2). plane1 dword1 = pair C=-1 = (0, in[0]) (real data).
// Two-phase staging (T14 async-STAGE): rows 0..19 staged up front; rows 20..35
//   global-loaded into regs BEFORE half-1 compute, LDS-written after it ->
//   read burst overlaps compute+stores at chip level.
__global__ __launch_bounds__(256)
void conv_bn_relu_pool(const float* __restrict__ x,
                       const float* __restrict__ conv_w,
                       const float* __restrict__ conv_b,
                       const float* __restrict__ gamma,
                       const float* __restrict__ beta,
                       const float* __restrict__ run_mean,
                       const float* __restrict__ run_var,
                       float* __restrict__ out)
{
    __shared__ __align__(16) uint32_t H[2 * HSZ];

    const int tid = threadIdx.x;
    const int b   = blockIdx.y;
    const int ty  = blockIdx.x * TILE_Y;
    const float* xb = x + (size_t)b * IMG * IMG;

    const int lane = tid & 63;
    const int wv   = tid >> 6;
    const int pp   = lane & 15;   // A-row pixel index == D channel column
    const int g    = lane >> 4;   // k-group == D pixel group

    // ---- B fragment + BN constants in-register ----
    const float* w = conv_w + pp * 25;
    float w0 = w[g*5+0], w1 = w[g*5+1], w2 = w[g*5+2], w3 = w[g*5+3], w4 = w[g*5+4];
    float e0 = (2*g   < 5) ? w[20 + 2*g]     : 0.f;
    float e1 = (2*g+1 < 5) ? w[20 + 2*g + 1] : 0.f;
    u32x4 bu;
    bu[0] = __builtin_bit_cast(uint32_t, __builtin_amdgcn_cvt_pkrtz(w0, w1));
    bu[1] = __builtin_bit_cast(uint32_t, __builtin_amdgcn_cvt_pkrtz(w2, w3));
    bu[2] = __builtin_bit_cast(uint32_t, __builtin_amdgcn_cvt_pkrtz(w4, 0.f));
    bu[3] = __builtin_bit_cast(uint32_t, __builtin_amdgcn_cvt_pkrtz(e0, e1));
    h8t B1 = __builtin_bit_cast(h8t, bu);
    float sc = gamma[pp] * rsqrtf(run_var[pp] + 1e-5f);
    float sh = fmaf(sc, conv_b[pp] - run_mean[pp], beta[pp]);

    // ---- phase A: stage rows 0..19 (float4-coalesced, both parity planes) ----
    for (int i = tid; i < A_ITEMS; i += 256) {
        int r = i / QW, q = i - r * QW;
        int gy = ty - 2 + r;
        int c  = 4 * q;
        f32x4 v = {0.f, 0.f, 0.f, 0.f};
        float v4 = 0.f;
        if ((unsigned)gy < IMG) {
            const float* row = xb + gy * IMG;
            v = *(const f32x4*)(row + c);
            if (q < QW - 1) v4 = row[c + 4];
        }
        uint32_t* base = H + r * HJ + 2 + (c >> 1);
        uint2 p0, p1;
        p0.x = __builtin_bit_cast(uint32_t, __builtin_amdgcn_cvt_pkrtz(v[0], v[1]));
        p0.y = __builtin_bit_cast(uint32_t, __builtin_amdgcn_cvt_pkrtz(v[2], v[3]));
        p1.x = __builtin_bit_cast(uint32_t, __builtin_amdgcn_cvt_pkrtz(v[1], v[2]));
        p1.y = __builtin_bit_cast(uint32_t, __builtin_amdgcn_cvt_pkrtz(v[3], v4));
        *(uint2*)(base)       = p0;
        *(uint2*)(base + HSZ) = p1;
    }
    // pad dwords {0,1},{114,115} for ALL 36 rows (disjoint from phase-B writes,
    // which only touch dwords 2..113). plane1 dword1 = pair C=-1 = (0, in[row][0]).
    if (tid < 2 * R_ROWS) {
        int pl = tid & 1, r = tid >> 1;
        int gy = ty - 2 + r;
        float f0 = 0.f;
        if (pl == 1 && (unsigned)gy < IMG) f0 = xb[gy * IMG];
        uint32_t pm1 = __builtin_bit_cast(uint32_t, __builtin_amdgcn_cvt_pkrtz(0.f, f0));
        uint32_t* row = H + pl * HSZ + r * HJ;
        row[0] = 0u;
        row[1] = pl ? pm1 : 0u;
        *(uint2*)(row + 114) = make_uint2(0u, 0u);
    }
    __syncthreads();

    // ---- issue phase-B global loads (rows 20..35) into registers NOW ----
    f32x4 pv[4];
    float pw[4];
    #pragma unroll
    for (int k = 0; k < 4; ++k) {
        int i = A_ITEMS + tid + 256 * k;
        pv[k] = (f32x4){0.f, 0.f, 0.f, 0.f};
        pw[k] = 0.f;
        if (i < T_ITEMS) {
            int r = i / QW, q = i - r * QW;
            int gy = ty - 2 + r;
            int c  = 4 * q;
            if ((unsigned)gy < IMG) {
                const float* row = xb + gy * IMG;
                pv[k] = *(const f32x4*)(row + c);
                if (q < QW - 1) pw[k] = row[c + 4];
            }
        }
    }

    const uint32_t* Hq = H + (pp & 1) * HSZ + (pp >> 1) + 1;
    float* outb = out + ((size_t)b * NCH + pp) * (OUT_DIM * OUT_DIM);

    // Each half: every wave computes 2 pooled rows x full 112-wide
    // (wave wv owns conv rows 16h + 4wv .. +3; 14 subtiles x 2 MFMAs each).
    auto compute_half = [&](int h) {
        #pragma unroll
        for (int s = 0; s < 2; ++s) {
            const int y0 = 16 * h + 4 * wv + 2 * s;              // conv rows y0, y0+1
            const int oy = blockIdx.x * 16 + 8 * h + 2 * wv + s; // global pooled row
            const uint32_t* rA = Hq + (y0 + g) * HJ;             // dy = g rows
            const uint32_t* r4 = Hq + (y0 + 4) * HJ + g;         // dy = 4 row
            float* orow = outb + oy * OUT_DIM + 2 * g;

            #pragma unroll
            for (int sub = 0; sub < 14; ++sub) {
                const int j0 = sub * 8;
                f32x4 accA = {0.f, 0.f, 0.f, 0.f};
                f32x4 accB = {0.f, 0.f, 0.f, 0.f};

                u32x4 a1 = { rA[j0], rA[j0 + 1], rA[j0 + 2], r4[j0] };
                accA = __builtin_amdgcn_mfma_f32_16x16x32_f16(
                           __builtin_bit_cast(h8t, a1), B1, accA, 0, 0, 0);
                u32x4 c1 = { rA[j0 + HJ], rA[j0 + 1 + HJ], rA[j0 + 2 + HJ], r4[j0 + HJ] };
                accB = __builtin_amdgcn_mfma_f32_16x16x32_f16(
                           __builtin_bit_cast(h8t, c1), B1, accB, 0, 0, 0);

                // maxpool (commutes with monotone BN scale>0 + ReLU) then epilogue
                float m0 = fmaxf(fmaxf(accA[0], accA[1]), fmaxf(accB[0], accB[1]));
                float m1 = fmaxf(fmaxf(accA[2], accA[3]), fmaxf(accB[2], accB[3]));
                float y0v = fmaxf(fmaf(m0, sc, sh), 0.f);
                float y1v = fmaxf(fmaf(m1, sc, sh), 0.f);
                *(float2*)(orow + sub * 8) = make_float2(y0v, y1v);
            }
        }
    };

    compute_half(0);   // conv rows 0..15 (reads H rows 0..19 only)

    // ---- write phase-B rows to LDS (vmcnt wait was hidden under half-1) ----
    #pragma unroll
    for (int k = 0; k < 4; ++k) {
        int i = A_ITEMS + tid + 256 * k;
        if (i < T_ITEMS) {
            int r = i / QW, q = i - r * QW;
            int c = 4 * q;
            uint32_t* base = H + r * HJ + 2 + (c >> 1);
            uint2 p0, p1;
            p0.x = __builtin_bit_cast(uint32_t, __builtin_amdgcn_cvt_pkrtz(pv[k][0], pv[k][1]));
            p0.y = __builtin_bit_cast(uint32_t, __builtin_amdgcn_cvt_pkrtz(pv[k][2], pv[k][3]));
            p1.x = __builtin_bit_cast(uint32_t, __builtin_amdgcn_cvt_pkrtz(pv[k][1], pv[k][2]));
            p1.y = __builtin_bit_cast(uint32_t, __builtin_amdgcn_cvt_pkrtz(pv[k][3], pw[k]));
            *(uint2*)(base)       = p0;
            *(uint2*)(base + HSZ) = p1;
        }
    }
    __syncthreads();

    compute_half(1);   // conv rows 16..31 (reads H rows 16..35)
}

extern "C" void kernel_launch(void* const* d_in, const int* in_sizes, int n_in,
                              void* d_out, int out_size, void* d_ws, size_t ws_size,
                              hipStream_t stream) {
    const float* x        = (const float*)d_in[0];
    const float* conv_w   = (const float*)d_in[1];
    const float* conv_b   = (const float*)d_in[2];
    const float* gamma    = (const float*)d_in[3];
    const float* beta     = (const float*)d_in[4];
    const float* run_mean = (const float*)d_in[5];
    const float* run_var  = (const float*)d_in[6];
    float* out = (float*)d_out;

    dim3 grid(IMG / TILE_Y, 128);   // 7 strips x 128 batch
    dim3 block(256);
    conv_bn_relu_pool<<<grid, block, 0, stream>>>(
        x, conv_w, conv_b, gamma, beta, run_mean, run_var, out);
}

// Round 8
// 146.989 us; speedup vs baseline: 1.0668x; 1.0668x over previous
//
#include <hip/hip_runtime.h>
#include <stdint.h>

#define IMG 224
#define OUT_DIM 112
#define NCH 16
#define TILE_Y 16          // conv rows per block (full 224-wide strip)
#define R_ROWS 20          // TILE_Y + 4 halo rows
#define HJ 116             // dwords per plane row: 2 front pad + 112 pairs + 2 tail pad
#define HSZ (R_ROWS * HJ)  // dwords per parity plane
#define QW 56              // float4 quads per image row

typedef _Float16 h8t  __attribute__((ext_vector_type(8)));
typedef float    f32x4 __attribute__((ext_vector_type(4)));
typedef uint32_t u32x4 __attribute__((ext_vector_type(4)));

// Implicit-GEMM conv (M=16 pixels, N=16 ch, K=32 = 25 taps + zero pad), one
// mfma_f32_16x16x32_f16 per conv row per 16-pixel subtile. Verified mapping:
//   B lane (ch=l&15, g=l>>4): k=8g+j -> (dy=g, dx=j) j<5; j=6,7 -> (dy=4, dx=2g,2g+1)
//   A lane (pp=l&15, g=l>>4): pairs (dx0,1)(dx2,3)(dx4,junk*0) of row y+g
//                             + pair (dx 2g,2g+1) of row y+4
//   D lane (pp,g) reg r: pixel 4g+r, channel pp -> 2x2 pool in-lane + across rows.
// LDS: parity-split pair planes, pair C = (in[C], in[C+1]) at plane[C&1],
//   row dword 2 + floor(C/2). plane1 dword1 = pair C=-1 = (0, in[0]) (real data).
// Geometry: TILE_Y=16 -> grid 14x128 = 1792 blocks = EXACTLY 7 blocks/CU
//   (balanced makespan, no 3-vs-4 dispatch tail) and 18.6 KB LDS -> ~7 waves/SIMD
//   of latency hiding. (R7's async-STAGE split regressed -8.7us: reverted.)
__global__ __launch_bounds__(256)
void conv_bn_relu_pool(const float* __restrict__ x,
                       const float* __restrict__ conv_w,
                       const float* __restrict__ conv_b,
                       const float* __restrict__ gamma,
                       const float* __restrict__ beta,
                       const float* __restrict__ run_mean,
                       const float* __restrict__ run_var,
                       float* __restrict__ out)
{
    __shared__ __align__(16) uint32_t H[2 * HSZ];

    const int tid = threadIdx.x;
    const int b   = blockIdx.y;
    const int ty  = blockIdx.x * TILE_Y;
    const float* xb = x + (size_t)b * IMG * IMG;

    const int lane = tid & 63;
    const int wv   = tid >> 6;
    const int pp   = lane & 15;   // A-row pixel index == D channel column
    const int g    = lane >> 4;   // k-group == D pixel group

    // ---- B fragment + BN constants in-register ----
    const float* w = conv_w + pp * 25;
    float w0 = w[g*5+0], w1 = w[g*5+1], w2 = w[g*5+2], w3 = w[g*5+3], w4 = w[g*5+4];
    float e0 = (2*g   < 5) ? w[20 + 2*g]     : 0.f;
    float e1 = (2*g+1 < 5) ? w[20 + 2*g + 1] : 0.f;
    u32x4 bu;
    bu[0] = __builtin_bit_cast(uint32_t, __builtin_amdgcn_cvt_pkrtz(w0, w1));
    bu[1] = __builtin_bit_cast(uint32_t, __builtin_amdgcn_cvt_pkrtz(w2, w3));
    bu[2] = __builtin_bit_cast(uint32_t, __builtin_amdgcn_cvt_pkrtz(w4, 0.f));
    bu[3] = __builtin_bit_cast(uint32_t, __builtin_amdgcn_cvt_pkrtz(e0, e1));
    h8t B1 = __builtin_bit_cast(h8t, bu);
    float sc = gamma[pp] * rsqrtf(run_var[pp] + 1e-5f);
    float sh = fmaf(sc, conv_b[pp] - run_mean[pp], beta[pp]);

    // ---- stage strip: float4-coalesced, both parity planes, aligned b64 writes ----
    for (int i = tid; i < R_ROWS * QW; i += 256) {
        int r = i / QW, q = i - r * QW;
        int gy = ty - 2 + r;
        int c  = 4 * q;
        f32x4 v = {0.f, 0.f, 0.f, 0.f};
        float v4 = 0.f;
        if ((unsigned)gy < IMG) {
            const float* row = xb + gy * IMG;
            v = *(const f32x4*)(row + c);
            if (q < QW - 1) v4 = row[c + 4];
        }
        uint32_t* base = H + r * HJ + 2 + (c >> 1);
        uint2 p0, p1;
        p0.x = __builtin_bit_cast(uint32_t, __builtin_amdgcn_cvt_pkrtz(v[0], v[1]));
        p0.y = __builtin_bit_cast(uint32_t, __builtin_amdgcn_cvt_pkrtz(v[2], v[3]));
        p1.x = __builtin_bit_cast(uint32_t, __builtin_amdgcn_cvt_pkrtz(v[1], v[2]));
        p1.y = __builtin_bit_cast(uint32_t, __builtin_amdgcn_cvt_pkrtz(v[3], v4));
        *(uint2*)(base)       = p0;
        *(uint2*)(base + HSZ) = p1;
    }
    // pad dwords {0,1} and {114,115} of every plane row (disjoint from staging).
    // plane1 dword1 = pair C=-1 = (0, in[row][0]) -- carries real data.
    if (tid < 2 * R_ROWS) {
        int pl = tid & 1, r = tid >> 1;
        int gy = ty - 2 + r;
        float f0 = 0.f;
        if (pl == 1 && (unsigned)gy < IMG) f0 = xb[gy * IMG];
        uint32_t pm1 = __builtin_bit_cast(uint32_t, __builtin_amdgcn_cvt_pkrtz(0.f, f0));
        uint32_t* row = H + pl * HSZ + r * HJ;
        row[0] = 0u;
        row[1] = pl ? pm1 : 0u;
        *(uint2*)(row + 114) = make_uint2(0u, 0u);
    }
    __syncthreads();

    const uint32_t* Hq = H + (pp & 1) * HSZ + (pp >> 1) + 1;
    float* outb = out + ((size_t)b * NCH + pp) * (OUT_DIM * OUT_DIM);

    // Each wave: 2 pooled rows x full 112-wide (14 subtiles x 2 MFMAs each).
    #pragma unroll
    for (int s = 0; s < 2; ++s) {
        const int y0 = 4 * wv + 2 * s;                   // conv rows y0, y0+1
        const int oy = blockIdx.x * 8 + 2 * wv + s;      // global pooled row
        const uint32_t* rA = Hq + (y0 + g) * HJ;         // dy = g rows
        const uint32_t* r4 = Hq + (y0 + 4) * HJ + g;     // dy = 4 row
        float* orow = outb + oy * OUT_DIM + 2 * g;

        #pragma unroll
        for (int sub = 0; sub < 14; ++sub) {
            const int j0 = sub * 8;
            f32x4 accA = {0.f, 0.f, 0.f, 0.f};
            f32x4 accB = {0.f, 0.f, 0.f, 0.f};

            u32x4 a1 = { rA[j0], rA[j0 + 1], rA[j0 + 2], r4[j0] };
            accA = __builtin_amdgcn_mfma_f32_16x16x32_f16(
                       __builtin_bit_cast(h8t, a1), B1, accA, 0, 0, 0);
            u32x4 c1 = { rA[j0 + HJ], rA[j0 + 1 + HJ], rA[j0 + 2 + HJ], r4[j0 + HJ] };
            accB = __builtin_amdgcn_mfma_f32_16x16x32_f16(
                       __builtin_bit_cast(h8t, c1), B1, accB, 0, 0, 0);

            // maxpool (commutes with monotone BN scale>0 + ReLU) then epilogue
            float m0 = fmaxf(fmaxf(accA[0], accA[1]), fmaxf(accB[0], accB[1]));
            float m1 = fmaxf(fmaxf(accA[2], accA[3]), fmaxf(accB[2], accB[3]));
            float y0v = fmaxf(fmaf(m0, sc, sh), 0.f);
            float y1v = fmaxf(fmaf(m1, sc, sh), 0.f);
            *(float2*)(orow + sub * 8) = make_float2(y0v, y1v);
        }
    }
}

extern "C" void kernel_launch(void* const* d_in, const int* in_sizes, int n_in,
                              void* d_out, int out_size, void* d_ws, size_t ws_size,
                              hipStream_t stream) {
    const float* x        = (const float*)d_in[0];
    const float* conv_w   = (const float*)d_in[1];
    const float* conv_b   = (const float*)d_in[2];
    const float* gamma    = (const float*)d_in[3];
    const float* beta     = (const float*)d_in[4];
    const float* run_mean = (const float*)d_in[5];
    const float* run_var  = (const float*)d_in[6];
    float* out = (float*)d_out;

    dim3 grid(IMG / TILE_Y, 128);   // 14 strips x 128 batch = 1792 = 7.0 blocks/CU
    dim3 block(256);
    conv_bn_relu_pool<<<grid, block, 0, stream>>>(
        x, conv_w, conv_b, gamma, beta, run_mean, run_var, out);
}